// Round 1
// baseline (193.298 us; speedup 1.0000x reference)
//
#include <hip/hip_runtime.h>
#include <math.h>

#define NODES 4096
#define FEATS 256
#define BATCH 1024
#define LR_C 0.5f
#define SIGMA_C 70.4f

// decay params from iteration scalar (iteration=0 -> decay=1 exactly)
__device__ __forceinline__ void get_params(int it, float& lr, float& r2, float& i2r2) {
    float decay = __expf(-(float)it * (SIGMA_C / 100000.0f));
    float radius = SIGMA_C * decay + 1e-6f;
    lr = LR_C * decay;
    r2 = radius * radius;
    i2r2 = 1.0f / (2.0f * r2);
}

// ---- K0: w2[n] = sum_d W[n,d]^2. One wave per row.
__global__ __launch_bounds__(256) void k_w2(const float* __restrict__ Wm, float* __restrict__ w2) {
    int row = blockIdx.x * 4 + (threadIdx.x >> 6);
    int lane = threadIdx.x & 63;
    float4 v = *(const float4*)&Wm[(size_t)row * FEATS + lane * 4];
    float s = v.x * v.x + v.y * v.y + v.z * v.z + v.w * v.w;
#pragma unroll
    for (int off = 32; off > 0; off >>= 1) s += __shfl_down(s, off, 64);
    if (lane == 0) w2[row] = s;
}

// ---- K1: s[b,n] = w2[n] - 2 * (x @ W^T)[b,n].  64x64 tile, K-chunk 32.
__global__ __launch_bounds__(256) void k_gemm1(const float* __restrict__ X, const float* __restrict__ Wm,
                                               const float* __restrict__ w2, float* __restrict__ Sd) {
    __shared__ float As[32][68];  // x chunk, k-major: As[k][b_local]
    __shared__ float Bs[32][68];  // W chunk, k-major: Bs[k][n_local]
    const int n0 = blockIdx.x * 64;
    const int b0 = blockIdx.y * 64;
    const int t = threadIdx.x;
    const int tx = t & 15, ty = t >> 4;
    const int r0 = t >> 3;
    const int kq = (t & 7) * 4;
    float acc[4][4] = {};
    for (int k0 = 0; k0 < FEATS; k0 += 32) {
#pragma unroll
        for (int rr = r0; rr < 64; rr += 32) {
            float4 va = *(const float4*)&X[(size_t)(b0 + rr) * FEATS + k0 + kq];
            As[kq + 0][rr] = va.x; As[kq + 1][rr] = va.y; As[kq + 2][rr] = va.z; As[kq + 3][rr] = va.w;
            float4 vb = *(const float4*)&Wm[(size_t)(n0 + rr) * FEATS + k0 + kq];
            Bs[kq + 0][rr] = vb.x; Bs[kq + 1][rr] = vb.y; Bs[kq + 2][rr] = vb.z; Bs[kq + 3][rr] = vb.w;
        }
        __syncthreads();
#pragma unroll
        for (int k = 0; k < 32; ++k) {
            float4 a = *(const float4*)&As[k][ty * 4];
            float4 b = *(const float4*)&Bs[k][tx * 4];
            float av[4] = {a.x, a.y, a.z, a.w};
            float bv[4] = {b.x, b.y, b.z, b.w};
#pragma unroll
            for (int i = 0; i < 4; ++i)
#pragma unroll
                for (int j = 0; j < 4; ++j) acc[i][j] = fmaf(av[i], bv[j], acc[i][j]);
        }
        __syncthreads();
    }
    float4 w2v = *(const float4*)&w2[n0 + tx * 4];
    float w2a[4] = {w2v.x, w2v.y, w2v.z, w2v.w};
#pragma unroll
    for (int i = 0; i < 4; ++i) {
        float4 o;
        o.x = w2a[0] - 2.0f * acc[i][0];
        o.y = w2a[1] - 2.0f * acc[i][1];
        o.z = w2a[2] - 2.0f * acc[i][2];
        o.w = w2a[3] - 2.0f * acc[i][3];
        *(float4*)&Sd[(size_t)(b0 + ty * 4 + i) * NODES + n0 + tx * 4] = o;
    }
}

// ---- K2: per-sample argmin over 4096 nodes, first-occurrence ties.
__global__ __launch_bounds__(256) void k_argmin(const float* __restrict__ Sd, int* __restrict__ bmu,
                                                float* __restrict__ out1) {
    __shared__ float sv[256];
    __shared__ int si[256];
    const int b = blockIdx.x;
    const int t = threadIdx.x;
    const float* row = Sd + (size_t)b * NODES;
    float best = INFINITY;
    int bidx = 0;
#pragma unroll
    for (int j = 0; j < 16; ++j) {
        int n = j * 256 + t;  // ascending per thread -> strict < keeps first occurrence
        float v = row[n];
        if (v < best) { best = v; bidx = n; }
    }
    sv[t] = best; si[t] = bidx;
    __syncthreads();
    for (int g = 128; g > 0; g >>= 1) {
        if (t < g) {
            float v2 = sv[t + g]; int i2 = si[t + g];
            if (v2 < sv[t] || (v2 == sv[t] && i2 < si[t])) { sv[t] = v2; si[t] = i2; }
        }
        __syncthreads();
    }
    if (t == 0) { bmu[b] = si[0]; out1[b] = (float)si[0]; }
}

// ---- K3: S[n] = lr * sum_b in_radius * impact  (bmu staged in LDS)
__global__ __launch_bounds__(256) void k_S(const int* __restrict__ bmu, const int* __restrict__ itp,
                                           float* __restrict__ Svec) {
    __shared__ int sb[1024];
    const int t = threadIdx.x;
#pragma unroll
    for (int i = 0; i < 4; ++i) sb[t + i * 256] = bmu[t + i * 256];
    __syncthreads();
    float lr, r2, i2r2;
    get_params(itp[0], lr, r2, i2r2);
    const int n = blockIdx.x * 256 + t;
    const int ni = n >> 6, nj = n & 63;
    float s = 0.0f;
    for (int b = 0; b < BATCH; ++b) {
        int m = sb[b];
        int di = ni - (m >> 6);
        int dj = nj - (m & 63);
        float d2 = (float)(di * di + dj * dj);
        if (d2 <= r2) s += __expf(-d2 * i2r2);
    }
    Svec[n] = lr * s;
}

// ---- K4: U_partial[z] = lr_op[z-half]^T @ x, A synthesized on the fly.
__global__ __launch_bounds__(256) void k_gemm2(const float* __restrict__ X, const int* __restrict__ bmu,
                                               const int* __restrict__ itp, float* __restrict__ P) {
    __shared__ float As[32][68];  // lr_op: As[k][n_local]
    __shared__ float Bs[32][68];  // x:     Bs[k][d_local]
    const int d0 = blockIdx.x * 64;
    const int n0 = blockIdx.y * 64;
    const int z = blockIdx.z;
    const int t = threadIdx.x;
    const int tx = t & 15, ty = t >> 4;
    float lr, r2, i2r2;
    get_params(itp[0], lr, r2, i2r2);
    const int tile_i = blockIdx.y;  // node row index = n0>>6 (64-aligned tile)
    float acc[4][4] = {};
    const int ka = t >> 3;
    const int j0 = (t & 7) * 8;
    const int kb = t >> 4;
    const int dq = (t & 15) * 4;
    for (int c = 0; c < 512; c += 32) {
        const int b0 = z * 512 + c;
        {  // A staging: compute lr_op[b0+ka][n0+j0..j0+7]
            int m = bmu[b0 + ka];
            int bi = m >> 6, bj = m & 63;
            int di = tile_i - bi;
            float dif = (float)(di * di);
            float vals[8];
#pragma unroll
            for (int u = 0; u < 8; ++u) {
                int dj = (j0 + u) - bj;
                float d2 = dif + (float)(dj * dj);
                vals[u] = (d2 <= r2) ? lr * __expf(-d2 * i2r2) : 0.0f;
            }
            *(float4*)&As[ka][j0] = make_float4(vals[0], vals[1], vals[2], vals[3]);
            *(float4*)&As[ka][j0 + 4] = make_float4(vals[4], vals[5], vals[6], vals[7]);
        }
#pragma unroll
        for (int kk = kb; kk < 32; kk += 16) {
            float4 v = *(const float4*)&X[(size_t)(b0 + kk) * FEATS + d0 + dq];
            *(float4*)&Bs[kk][dq] = v;
        }
        __syncthreads();
#pragma unroll
        for (int k = 0; k < 32; ++k) {
            float4 a = *(const float4*)&As[k][ty * 4];
            float4 b = *(const float4*)&Bs[k][tx * 4];
            float av[4] = {a.x, a.y, a.z, a.w};
            float bv[4] = {b.x, b.y, b.z, b.w};
#pragma unroll
            for (int i = 0; i < 4; ++i)
#pragma unroll
                for (int j = 0; j < 4; ++j) acc[i][j] = fmaf(av[i], bv[j], acc[i][j]);
        }
        __syncthreads();
    }
#pragma unroll
    for (int i = 0; i < 4; ++i) {
        float4 o = make_float4(acc[i][0], acc[i][1], acc[i][2], acc[i][3]);
        *(float4*)&P[(size_t)z * NODES * FEATS + (size_t)(n0 + ty * 4 + i) * FEATS + d0 + tx * 4] = o;
    }
}

// ---- K5: out0 = w*(1 - S/B) + (P0+P1)/B
__global__ __launch_bounds__(256) void k_combine(const float* __restrict__ Wm, const float* __restrict__ P,
                                                 const float* __restrict__ Svec, float* __restrict__ out0) {
    const int g = blockIdx.x * 256 + threadIdx.x;  // float4 index
    const int n = g >> 6;                          // 64 float4s per node row
    const float invB = 1.0f / (float)BATCH;
    float4 w4 = *(const float4*)&Wm[(size_t)g * 4];
    float4 p0 = *(const float4*)&P[(size_t)g * 4];
    float4 p1 = *(const float4*)&P[(size_t)NODES * FEATS + (size_t)g * 4];
    float c = 1.0f - Svec[n] * invB;
    float4 o;
    o.x = w4.x * c + (p0.x + p1.x) * invB;
    o.y = w4.y * c + (p0.y + p1.y) * invB;
    o.z = w4.z * c + (p0.z + p1.z) * invB;
    o.w = w4.w * c + (p0.w + p1.w) * invB;
    *(float4*)&out0[(size_t)g * 4] = o;
}

extern "C" void kernel_launch(void* const* d_in, const int* in_sizes, int n_in,
                              void* d_out, int out_size, void* d_ws, size_t ws_size,
                              hipStream_t stream) {
    const float* X = (const float*)d_in[0];    // (1024, 256)
    const float* Wm = (const float*)d_in[1];   // (4096, 256)
    const int* itp = (const int*)d_in[2];      // scalar iteration
    float* out = (float*)d_out;                // [new_map 4096*256 | bmu 1024] as float32

    char* ws = (char*)d_ws;
    float* w2 = (float*)ws;                                        // 16 KB
    float* Sd = (float*)(ws + 16384);                              // 16 MB
    int* bmu = (int*)(ws + 16384 + 16777216);                      // 4 KB
    float* Svec = (float*)(ws + 16384 + 16777216 + 4096);          // 16 KB
    float* P = (float*)(ws + 16384 + 16777216 + 4096 + 16384);     // 8 MB (2 partials)

    k_w2<<<1024, 256, 0, stream>>>(Wm, w2);
    k_gemm1<<<dim3(64, 16), 256, 0, stream>>>(X, Wm, w2, Sd);
    k_argmin<<<1024, 256, 0, stream>>>(Sd, bmu, out + (size_t)NODES * FEATS);
    k_S<<<16, 256, 0, stream>>>(bmu, itp, Svec);
    k_gemm2<<<dim3(4, 64, 2), 256, 0, stream>>>(X, bmu, itp, P);
    k_combine<<<1024, 256, 0, stream>>>(Wm, P, Svec, out);
}

// Round 2
// 110.353 us; speedup vs baseline: 1.7516x; 1.7516x over previous
//
#include <hip/hip_runtime.h>
#include <math.h>

#define NODES 4096
#define FEATS 256
#define BATCH 1024
#define LR_C 0.5f
#define SIGMA_C 70.4f

typedef _Float16 f16x8 __attribute__((ext_vector_type(8)));
typedef float floatx4 __attribute__((ext_vector_type(4)));

__device__ __forceinline__ void get_params(int it, float& lr, float& r2, float& i2r2) {
    float decay = __expf(-(float)it * (SIGMA_C / 100000.0f));
    float radius = SIGMA_C * decay + 1e-6f;
    lr = LR_C * decay;
    r2 = radius * radius;
    i2r2 = 1.0f / (2.0f * r2);
}

// ---- P0: W -> fp16 copy + w2[n] = sum_d W[n,d]^2. 4 rows/block, wave per row.
__global__ __launch_bounds__(256) void k_prep_w(const float* __restrict__ Wm,
                                                _Float16* __restrict__ Wh, float* __restrict__ w2) {
    int row = blockIdx.x * 4 + (threadIdx.x >> 6);
    int lane = threadIdx.x & 63;
    float4 v = *(const float4*)&Wm[(size_t)row * FEATS + lane * 4];
    union { _Float16 h[4]; float2 f2; } u;
    u.h[0] = (_Float16)v.x; u.h[1] = (_Float16)v.y; u.h[2] = (_Float16)v.z; u.h[3] = (_Float16)v.w;
    *(float2*)&Wh[(size_t)row * FEATS + lane * 4] = u.f2;
    float s = v.x * v.x + v.y * v.y + v.z * v.z + v.w * v.w;
#pragma unroll
    for (int off = 32; off > 0; off >>= 1) s += __shfl_down(s, off, 64);
    if (lane == 0) w2[row] = s;
}

// ---- P1: x -> fp16 (b-major) AND fp16 transposed (d-major), 64x64 tiles via LDS.
__global__ __launch_bounds__(256) void k_prep_x(const float* __restrict__ X,
                                                _Float16* __restrict__ Xh, _Float16* __restrict__ XT) {
    __shared__ _Float16 T[64][72];
    const int b0 = blockIdx.x * 64;
    const int d0 = blockIdx.y * 64;
    const int t = threadIdx.x;
    {
        const int bl = t >> 2, dq = (t & 3) * 16;
        union { _Float16 h[16]; float4 q[2]; } u;
#pragma unroll
        for (int c = 0; c < 4; ++c) {
            float4 v = *(const float4*)&X[(size_t)(b0 + bl) * FEATS + d0 + dq + c * 4];
            u.h[c * 4 + 0] = (_Float16)v.x; u.h[c * 4 + 1] = (_Float16)v.y;
            u.h[c * 4 + 2] = (_Float16)v.z; u.h[c * 4 + 3] = (_Float16)v.w;
        }
        *(float4*)&Xh[(size_t)(b0 + bl) * FEATS + d0 + dq] = u.q[0];
        *(float4*)&Xh[(size_t)(b0 + bl) * FEATS + d0 + dq + 8] = u.q[1];
#pragma unroll
        for (int c = 0; c < 16; ++c) T[bl][dq + c] = u.h[c];
    }
    __syncthreads();
    {
        const int dl = t >> 2, bq = (t & 3) * 16;
        union { _Float16 h[16]; float4 q[2]; } u;
#pragma unroll
        for (int c = 0; c < 16; ++c) u.h[c] = T[bq + c][dl];
        *(float4*)&XT[(size_t)(d0 + dl) * BATCH + b0 + bq] = u.q[0];
        *(float4*)&XT[(size_t)(d0 + dl) * BATCH + b0 + bq + 8] = u.q[1];
    }
}

// ---- G1: approx sqd[b,n] = w2[n] - 2*(x@W^T) via f16 MFMA, stored fp16.
// 64x64 tile, 4 waves each computing a 32x32 quadrant (2x2 frags of 16x16x32).
__global__ __launch_bounds__(256) void k_gemm1(const _Float16* __restrict__ Xh, const _Float16* __restrict__ Wh,
                                               const float* __restrict__ w2, _Float16* __restrict__ Sd) {
    __shared__ _Float16 As[64][40];
    __shared__ _Float16 Bs[64][40];
    const int n0 = blockIdx.x * 64;
    const int b0 = blockIdx.y * 64;
    const int t = threadIdx.x;
    const int wave = t >> 6, lane = t & 63;
    const int wm = wave & 1, wn = wave >> 1;
    const int lm = lane & 15, quad = lane >> 4;
    const int srow = t >> 2, skoff = (t & 3) * 8;
    floatx4 acc[2][2] = {};
    for (int k0 = 0; k0 < FEATS; k0 += 32) {
        *(float4*)&As[srow][skoff] = *(const float4*)&Xh[(size_t)(b0 + srow) * FEATS + k0 + skoff];
        *(float4*)&Bs[srow][skoff] = *(const float4*)&Wh[(size_t)(n0 + srow) * FEATS + k0 + skoff];
        __syncthreads();
        f16x8 af0 = *(f16x8*)&As[wm * 32 + lm][quad * 8];
        f16x8 af1 = *(f16x8*)&As[wm * 32 + 16 + lm][quad * 8];
        f16x8 bf0 = *(f16x8*)&Bs[wn * 32 + lm][quad * 8];
        f16x8 bf1 = *(f16x8*)&Bs[wn * 32 + 16 + lm][quad * 8];
        acc[0][0] = __builtin_amdgcn_mfma_f32_16x16x32_f16(af0, bf0, acc[0][0], 0, 0, 0);
        acc[0][1] = __builtin_amdgcn_mfma_f32_16x16x32_f16(af0, bf1, acc[0][1], 0, 0, 0);
        acc[1][0] = __builtin_amdgcn_mfma_f32_16x16x32_f16(af1, bf0, acc[1][0], 0, 0, 0);
        acc[1][1] = __builtin_amdgcn_mfma_f32_16x16x32_f16(af1, bf1, acc[1][1], 0, 0, 0);
        __syncthreads();
    }
#pragma unroll
    for (int i = 0; i < 2; ++i)
#pragma unroll
        for (int j = 0; j < 2; ++j) {
            int col = n0 + wn * 32 + j * 16 + lm;
            float w2c = w2[col];
#pragma unroll
            for (int r = 0; r < 4; ++r) {
                int row = b0 + wm * 32 + i * 16 + quad * 4 + r;
                Sd[(size_t)row * NODES + col] = (_Float16)(w2c - 2.0f * acc[i][j][r]);
            }
        }
}

// ---- A: argmin with exact fp32 refine over candidates within margin.
__global__ __launch_bounds__(256) void k_argmin(const _Float16* __restrict__ Sd, const float* __restrict__ X,
                                                const float* __restrict__ Wm, const float* __restrict__ w2,
                                                int* __restrict__ bmu, float* __restrict__ out1) {
    __shared__ float sv[256];
    __shared__ int si[256];
    __shared__ float red[256];
    __shared__ int cand[128];
    __shared__ int cnt;
    const int b = blockIdx.x;
    const int t = threadIdx.x;
    const _Float16* row = Sd + (size_t)b * NODES;
    float v[16];
#pragma unroll
    for (int j = 0; j < 2; ++j) {
        f16x8 h = *(const f16x8*)&row[j * 2048 + t * 8];
#pragma unroll
        for (int u = 0; u < 8; ++u) v[j * 8 + u] = (float)h[u];
    }
    float best = INFINITY;
    int bidx = 0;
#pragma unroll
    for (int j = 0; j < 2; ++j)
#pragma unroll
        for (int u = 0; u < 8; ++u) {
            int n = j * 2048 + t * 8 + u;  // ascending within thread -> first occurrence
            if (v[j * 8 + u] < best) { best = v[j * 8 + u]; bidx = n; }
        }
    sv[t] = best; si[t] = bidx;
    if (t == 0) cnt = 0;
    __syncthreads();
    for (int g = 128; g > 0; g >>= 1) {
        if (t < g) {
            float v2 = sv[t + g]; int i2 = si[t + g];
            if (v2 < sv[t] || (v2 == sv[t] && i2 < si[t])) { sv[t] = v2; si[t] = i2; }
        }
        __syncthreads();
    }
    const float thr = sv[0] + 0.4f;  // margin >> fp16-GEMM + fp16-storage error
#pragma unroll
    for (int j = 0; j < 2; ++j)
#pragma unroll
        for (int u = 0; u < 8; ++u) {
            if (v[j * 8 + u] <= thr) {
                int p = atomicAdd(&cnt, 1);
                if (p < 128) cand[p] = j * 2048 + t * 8 + u;
            }
        }
    __syncthreads();
    const int C = cnt < 128 ? cnt : 128;
    const float xv = X[(size_t)b * FEATS + t];
    float bestv = INFINITY;
    int besti = NODES;
    for (int c = 0; c < C; ++c) {
        int n = cand[c];
        red[t] = xv * Wm[(size_t)n * FEATS + t];
        __syncthreads();
        for (int g = 128; g > 0; g >>= 1) {
            if (t < g) red[t] += red[t + g];
            __syncthreads();
        }
        if (t == 0) {
            float ex = w2[n] - 2.0f * red[0];
            if (ex < bestv || (ex == bestv && n < besti)) { bestv = ex; besti = n; }
        }
        __syncthreads();
    }
    if (t == 0) { bmu[b] = besti; out1[b] = (float)besti; }
}

// ---- L: lr_op^T as fp16 (NODES x BATCH) + Svec[n] = sum_b lr_op. exp via LDS table.
__global__ __launch_bounds__(256) void k_lrop(const int* __restrict__ bmu, const int* __restrict__ itp,
                                              _Float16* __restrict__ lrT, float* __restrict__ Svec) {
    __shared__ int bmu_s[1024];
    __shared__ float texp[64];
    __shared__ float red4[4];
    const int t = threadIdx.x;
#pragma unroll
    for (int j = 0; j < 4; ++j) bmu_s[t + j * 256] = bmu[t + j * 256];
    float lr, r2, i2r2;
    get_params(itp[0], lr, r2, i2r2);
    if (t < 64) texp[t] = __expf(-(float)(t * t) * i2r2);
    __syncthreads();
    const int n = blockIdx.x * 2 + (t >> 7);
    const int b0 = (t & 127) * 8;
    const int ni = n >> 6, nj = n & 63;
    float s = 0.0f;
    union { _Float16 h[8]; float4 q; } u;
#pragma unroll
    for (int c = 0; c < 8; ++c) {
        int m = bmu_s[b0 + c];
        int di = ni - (m >> 6); di = di < 0 ? -di : di;
        int dj = nj - (m & 63); dj = dj < 0 ? -dj : dj;
        int d2 = di * di + dj * dj;
        float val = ((float)d2 <= r2) ? lr * texp[di] * texp[dj] : 0.0f;
        u.h[c] = (_Float16)val;
        s += val;
    }
    *(float4*)&lrT[(size_t)n * BATCH + b0] = u.q;
    const int lane = t & 63, wave = t >> 6;
#pragma unroll
    for (int off = 32; off > 0; off >>= 1) s += __shfl_down(s, off, 64);
    if (lane == 0) red4[wave] = s;
    __syncthreads();
    if (t < 2) Svec[blockIdx.x * 2 + t] = red4[2 * t] + red4[2 * t + 1];
}

// ---- G2: P[z] = lr_op[z-half]^T @ x via f16 MFMA. K-split 2 for occupancy.
__global__ __launch_bounds__(256) void k_gemm2(const _Float16* __restrict__ lrT, const _Float16* __restrict__ XT,
                                               float* __restrict__ P) {
    __shared__ _Float16 As[64][40];
    __shared__ _Float16 Bs[64][40];
    const int d0 = blockIdx.x * 64;
    const int n0 = blockIdx.y * 64;
    const int z = blockIdx.z;
    const int t = threadIdx.x;
    const int wave = t >> 6, lane = t & 63;
    const int wm = wave & 1, wn = wave >> 1;
    const int lm = lane & 15, quad = lane >> 4;
    const int srow = t >> 2, skoff = (t & 3) * 8;
    const size_t kbase = (size_t)z * 512;
    floatx4 acc[2][2] = {};
    for (int k0 = 0; k0 < 512; k0 += 32) {
        *(float4*)&As[srow][skoff] = *(const float4*)&lrT[(size_t)(n0 + srow) * BATCH + kbase + k0 + skoff];
        *(float4*)&Bs[srow][skoff] = *(const float4*)&XT[(size_t)(d0 + srow) * BATCH + kbase + k0 + skoff];
        __syncthreads();
        f16x8 af0 = *(f16x8*)&As[wm * 32 + lm][quad * 8];
        f16x8 af1 = *(f16x8*)&As[wm * 32 + 16 + lm][quad * 8];
        f16x8 bf0 = *(f16x8*)&Bs[wn * 32 + lm][quad * 8];
        f16x8 bf1 = *(f16x8*)&Bs[wn * 32 + 16 + lm][quad * 8];
        acc[0][0] = __builtin_amdgcn_mfma_f32_16x16x32_f16(af0, bf0, acc[0][0], 0, 0, 0);
        acc[0][1] = __builtin_amdgcn_mfma_f32_16x16x32_f16(af0, bf1, acc[0][1], 0, 0, 0);
        acc[1][0] = __builtin_amdgcn_mfma_f32_16x16x32_f16(af1, bf0, acc[1][0], 0, 0, 0);
        acc[1][1] = __builtin_amdgcn_mfma_f32_16x16x32_f16(af1, bf1, acc[1][1], 0, 0, 0);
        __syncthreads();
    }
    float* Pz = P + (size_t)z * NODES * FEATS;
#pragma unroll
    for (int i = 0; i < 2; ++i)
#pragma unroll
        for (int j = 0; j < 2; ++j) {
            int col = d0 + wn * 32 + j * 16 + lm;
#pragma unroll
            for (int r = 0; r < 4; ++r) {
                int row = n0 + wm * 32 + i * 16 + quad * 4 + r;
                Pz[(size_t)row * FEATS + col] = acc[i][j][r];
            }
        }
}

// ---- C: out0 = w*(1 - S/B) + (P0+P1)/B
__global__ __launch_bounds__(256) void k_combine(const float* __restrict__ Wm, const float* __restrict__ P,
                                                 const float* __restrict__ Svec, float* __restrict__ out0) {
    const int g = blockIdx.x * 256 + threadIdx.x;
    const int n = g >> 6;
    const float invB = 1.0f / (float)BATCH;
    float4 w4 = *(const float4*)&Wm[(size_t)g * 4];
    float4 p0 = *(const float4*)&P[(size_t)g * 4];
    float4 p1 = *(const float4*)&P[(size_t)NODES * FEATS + (size_t)g * 4];
    float c = 1.0f - Svec[n] * invB;
    float4 o;
    o.x = w4.x * c + (p0.x + p1.x) * invB;
    o.y = w4.y * c + (p0.y + p1.y) * invB;
    o.z = w4.z * c + (p0.z + p1.z) * invB;
    o.w = w4.w * c + (p0.w + p1.w) * invB;
    *(float4*)&out0[(size_t)g * 4] = o;
}

extern "C" void kernel_launch(void* const* d_in, const int* in_sizes, int n_in,
                              void* d_out, int out_size, void* d_ws, size_t ws_size,
                              hipStream_t stream) {
    const float* X = (const float*)d_in[0];    // (1024, 256)
    const float* Wm = (const float*)d_in[1];   // (4096, 256)
    const int* itp = (const int*)d_in[2];      // scalar iteration
    float* out = (float*)d_out;

    char* ws = (char*)d_ws;
    float* w2       = (float*)(ws + 0);              // 16 KB
    _Float16* Xh    = (_Float16*)(ws + 16384);       // 512 KB
    _Float16* XT    = (_Float16*)(ws + 540672);      // 512 KB
    _Float16* Wh    = (_Float16*)(ws + 1064960);     // 2 MB
    int* bmu        = (int*)(ws + 3162112);          // 4 KB
    float* Svec     = (float*)(ws + 3166208);        // 16 KB
    _Float16* Sd    = (_Float16*)(ws + 3182592);     // 8 MB (fp16 approx sqd; reused as lrT)
    _Float16* lrT   = (_Float16*)(ws + 3182592);     // aliases Sd (dead after argmin)
    float* P        = (float*)(ws + 11571200);       // 8 MB (2 fp32 partials)

    k_prep_w<<<1024, 256, 0, stream>>>(Wm, Wh, w2);
    k_prep_x<<<dim3(16, 4), 256, 0, stream>>>(X, Xh, XT);
    k_gemm1<<<dim3(64, 16), 256, 0, stream>>>(Xh, Wh, w2, Sd);
    k_argmin<<<1024, 256, 0, stream>>>(Sd, X, Wm, w2, bmu, out + (size_t)NODES * FEATS);
    k_lrop<<<2048, 256, 0, stream>>>(bmu, itp, lrT, Svec);
    k_gemm2<<<dim3(4, 64, 2), 256, 0, stream>>>(lrT, XT, P);
    k_combine<<<1024, 256, 0, stream>>>(Wm, P, Svec, out);
}